// Round 2
// baseline (169.858 us; speedup 1.0000x reference)
//
#include <hip/hip_runtime.h>
#include <hip/hip_bf16.h>

#define N_NODES 50000
#define D_IN    128
#define D_OUT   64
#define N_EDGES 800000

// ---------------------------------------------------------------------------
// Kernel 1: X' = X @ W  (fp32, vector ALU — no fp32 MFMA on CDNA4)
// W (128x64 = 32KB) staged in LDS once per block.
// Each thread: 4 rows x 1 col. Lanes j=0..63 cover all 64 output cols, so
// W LDS reads are 2-way bank aliased (free, m136) and X' stores are fully
// coalesced. 4-row blocking amortizes each W LDS read over 4 FMAs.
// ---------------------------------------------------------------------------
__global__ __launch_bounds__(256) void gemm_xw(const float* __restrict__ X,
                                               const float* __restrict__ W,
                                               float* __restrict__ Xp) {
    __shared__ float Wlds[D_IN * D_OUT]; // 32 KB
    for (int t = threadIdx.x; t < (D_IN * D_OUT) / 4; t += 256) {
        reinterpret_cast<float4*>(Wlds)[t] = reinterpret_cast<const float4*>(W)[t];
    }
    __syncthreads();

    const int tid = blockIdx.x * 256 + threadIdx.x;
    const int j  = tid & 63;       // output col (lane)
    const int g  = tid >> 6;       // row group
    const int i0 = g * 4;
    if (i0 >= N_NODES) return;

    const float4* __restrict__ X4 = reinterpret_cast<const float4*>(X);
    float acc0 = 0.f, acc1 = 0.f, acc2 = 0.f, acc3 = 0.f;

    #pragma unroll 4
    for (int kk = 0; kk < D_IN / 4; ++kk) {
        // wave-uniform 16B loads (g uniform within a wave) -> broadcast, L1-hot
        float4 x0 = X4[(size_t)(i0 + 0) * (D_IN / 4) + kk];
        float4 x1 = X4[(size_t)(i0 + 1) * (D_IN / 4) + kk];
        float4 x2 = X4[(size_t)(i0 + 2) * (D_IN / 4) + kk];
        float4 x3 = X4[(size_t)(i0 + 3) * (D_IN / 4) + kk];
        float w0 = Wlds[(4 * kk + 0) * D_OUT + j];
        float w1 = Wlds[(4 * kk + 1) * D_OUT + j];
        float w2 = Wlds[(4 * kk + 2) * D_OUT + j];
        float w3 = Wlds[(4 * kk + 3) * D_OUT + j];
        acc0 += x0.x * w0 + x0.y * w1 + x0.z * w2 + x0.w * w3;
        acc1 += x1.x * w0 + x1.y * w1 + x1.z * w2 + x1.w * w3;
        acc2 += x2.x * w0 + x2.y * w1 + x2.z * w2 + x2.w * w3;
        acc3 += x3.x * w0 + x3.y * w1 + x3.z * w2 + x3.w * w3;
    }
    Xp[(size_t)(i0 + 0) * D_OUT + j] = acc0;
    Xp[(size_t)(i0 + 1) * D_OUT + j] = acc1;
    Xp[(size_t)(i0 + 2) * D_OUT + j] = acc2;
    Xp[(size_t)(i0 + 3) * D_OUT + j] = acc3;
}

// ---------------------------------------------------------------------------
// Kernel 2: row_ptr[i] = lower_bound(row_index, i), i in [0, N_NODES]
// row_index is sorted. Per-lane independent binary search; top tree levels
// are cache-hot across lanes -> latency hidden by 50k-way TLP.
// ---------------------------------------------------------------------------
__global__ __launch_bounds__(256) void build_rowptr(const int* __restrict__ row,
                                                    int* __restrict__ rowptr) {
    const int i = blockIdx.x * 256 + threadIdx.x;
    if (i > N_NODES) return;
    int lo = 0, hi = N_EDGES;
    while (lo < hi) {
        int mid = (lo + hi) >> 1;
        if (row[mid] < i) lo = mid + 1; else hi = mid;
    }
    rowptr[i] = lo;
}

// ---------------------------------------------------------------------------
// Kernel 3: out[i,:] = sum_{e in [rowptr[i], rowptr[i+1])} Xp[col[e], :]
// One wave per row, lane j owns column j -> each edge gather is one fully
// coalesced 256B transaction; Xp (12.8MB) is L3-resident so gathers are
// cache-served. 8-deep load batching for memory-level parallelism.
// Every row written exactly once (empty rows write 0) -> no memset, no
// atomics, deterministic.
// ---------------------------------------------------------------------------
__global__ __launch_bounds__(256) void aggregate(const float* __restrict__ Xp,
                                                 const int* __restrict__ col,
                                                 const int* __restrict__ rowptr,
                                                 float* __restrict__ out) {
    const int wid = (blockIdx.x * 256 + threadIdx.x) >> 6; // row id
    const int j   = threadIdx.x & 63;                      // output col

    const int lo = rowptr[wid];
    const int hi = rowptr[wid + 1];

    float acc = 0.f;
    int e = lo;
    for (; e + 8 <= hi; e += 8) {
        // issue 8 independent gathers before consuming -> vmcnt pipelining
        float v0 = Xp[(size_t)col[e + 0] * D_OUT + j];
        float v1 = Xp[(size_t)col[e + 1] * D_OUT + j];
        float v2 = Xp[(size_t)col[e + 2] * D_OUT + j];
        float v3 = Xp[(size_t)col[e + 3] * D_OUT + j];
        float v4 = Xp[(size_t)col[e + 4] * D_OUT + j];
        float v5 = Xp[(size_t)col[e + 5] * D_OUT + j];
        float v6 = Xp[(size_t)col[e + 6] * D_OUT + j];
        float v7 = Xp[(size_t)col[e + 7] * D_OUT + j];
        acc += ((v0 + v1) + (v2 + v3)) + ((v4 + v5) + (v6 + v7));
    }
    for (; e < hi; ++e) {
        acc += Xp[(size_t)col[e] * D_OUT + j];
    }
    out[(size_t)wid * D_OUT + j] = acc;
}

// ---------------------------------------------------------------------------
extern "C" void kernel_launch(void* const* d_in, const int* in_sizes, int n_in,
                              void* d_out, int out_size, void* d_ws, size_t ws_size,
                              hipStream_t stream) {
    const float* X   = (const float*)d_in[0];
    const float* W   = (const float*)d_in[1];
    const int*   row = (const int*)d_in[2];
    const int*   col = (const int*)d_in[3];
    float*       out = (float*)d_out;

    // workspace layout: Xp [50000*64 f32 = 12.8MB] | rowptr [(N+1) i32]
    float* Xp     = (float*)d_ws;
    int*   rowptr = (int*)((char*)d_ws + (size_t)N_NODES * D_OUT * sizeof(float));

    // GEMM: 50000/4 row-groups * 64 lanes / 256 threads = 3125 blocks
    hipLaunchKernelGGL(gemm_xw, dim3((N_NODES / 4 * 64) / 256), dim3(256), 0, stream,
                       X, W, Xp);
    // row_ptr: N_NODES+1 searches
    hipLaunchKernelGGL(build_rowptr, dim3((N_NODES + 1 + 255) / 256), dim3(256), 0, stream,
                       row, rowptr);
    // aggregation: one wave per row -> 50000 waves = 12500 blocks of 4 waves
    hipLaunchKernelGGL(aggregate, dim3((N_NODES * 64) / 256), dim3(256), 0, stream,
                       Xp, col, rowptr, out);
}

// Round 3
// 129.873 us; speedup vs baseline: 1.3079x; 1.3079x over previous
//
#include <hip/hip_runtime.h>
#include <hip/hip_bf16.h>

#define N_NODES 50000
#define D_IN    128
#define D_OUT   64
#define N_EDGES 800000
#define GROWS   64   // rows per block in gemm tile

// ---------------------------------------------------------------------------
// Kernel 1: X' = X @ W  (fp32, vector ALU — no fp32 MFMA on CDNA4)
// R2 post-mortem: previous version was latency-bound (25% VALUBusy, 5% HBM) —
// wave-uniform X loads issued 128 VMEM/wave for 2KB of unique data.
// Fix: classic LDS tiling. Block = 256 threads = 64-row tile.
//   - X tile [64][128] staged via fully-coalesced float4 loads (8/thread).
//   - W [128][64] staged once (reused across all 32 k-chunks).
//   - Each thread computes 4 rows x 4 cols from LDS: per k-chunk
//     8x ds_read_b128 + 64 FMA -> VALU-bound (~5.2us floor).
// Xs padded +4 floats: 4-row-group read stride = 528B -> banks {0,16} ->
// 2-way aliasing (free, m136). W reads 2-way + broadcast. No conflicts.
// LDS 66.5KB -> 2 blocks/CU.
// ---------------------------------------------------------------------------
__global__ __launch_bounds__(256, 2) void gemm_xw(const float* __restrict__ X,
                                                  const float* __restrict__ W,
                                                  float* __restrict__ Xp) {
    __shared__ float Xs[GROWS][D_IN + 4];   // stride 132 floats = 528 B
    __shared__ float Ws[D_IN][D_OUT];       // 32 KB

    const int tid  = threadIdx.x;
    const int row0 = blockIdx.x * GROWS;

    // stage W: 2048 float4 / 256 threads = 8 each, coalesced
    {
        const float4* W4  = reinterpret_cast<const float4*>(W);
        float4*       Ws4 = reinterpret_cast<float4*>(&Ws[0][0]);
        #pragma unroll
        for (int t = 0; t < 8; ++t) Ws4[tid + 256 * t] = W4[tid + 256 * t];
    }
    // stage X tile: 64 rows x 32 float4 = 2048 float4 / 256 threads = 8 each
    {
        const float4* X4 = reinterpret_cast<const float4*>(X);
        #pragma unroll
        for (int t = 0; t < 8; ++t) {
            const int s  = tid + 256 * t;   // 0..2047
            const int r  = s >> 5;          // 0..63
            const int kq = s & 31;          // float4 index within row
            const int gr = row0 + r;
            float4 v = make_float4(0.f, 0.f, 0.f, 0.f);
            if (gr < N_NODES) v = X4[(size_t)gr * (D_IN / 4) + kq];
            *reinterpret_cast<float4*>(&Xs[r][kq * 4]) = v;
        }
    }
    __syncthreads();

    const int tc = tid & 15;   // col group
    const int tg = tid >> 4;   // row group
    const int c0 = tc * 4;
    const int r0 = tg * 4;

    float acc[4][4];
    #pragma unroll
    for (int r = 0; r < 4; ++r)
        #pragma unroll
        for (int c = 0; c < 4; ++c) acc[r][c] = 0.f;

    #pragma unroll 4
    for (int kq = 0; kq < 32; ++kq) {
        const int k0 = kq * 4;
        float4 xa[4], wb[4];
        #pragma unroll
        for (int r = 0; r < 4; ++r)
            xa[r] = *reinterpret_cast<const float4*>(&Xs[r0 + r][k0]);
        #pragma unroll
        for (int kk = 0; kk < 4; ++kk)
            wb[kk] = *reinterpret_cast<const float4*>(&Ws[k0 + kk][c0]);
        #pragma unroll
        for (int r = 0; r < 4; ++r) {
            const float x0 = xa[r].x, x1 = xa[r].y, x2 = xa[r].z, x3 = xa[r].w;
            acc[r][0] += x0 * wb[0].x + x1 * wb[1].x + x2 * wb[2].x + x3 * wb[3].x;
            acc[r][1] += x0 * wb[0].y + x1 * wb[1].y + x2 * wb[2].y + x3 * wb[3].y;
            acc[r][2] += x0 * wb[0].z + x1 * wb[1].z + x2 * wb[2].z + x3 * wb[3].z;
            acc[r][3] += x0 * wb[0].w + x1 * wb[1].w + x2 * wb[2].w + x3 * wb[3].w;
        }
    }

    #pragma unroll
    for (int r = 0; r < 4; ++r) {
        const int gr = row0 + r0 + r;
        if (gr < N_NODES) {
            float4 v = make_float4(acc[r][0], acc[r][1], acc[r][2], acc[r][3]);
            *reinterpret_cast<float4*>(&Xp[(size_t)gr * D_OUT + c0]) = v;
        }
    }
}

// ---------------------------------------------------------------------------
// Kernel 2: row_ptr[i] = lower_bound(row_index, i)
// ---------------------------------------------------------------------------
__global__ __launch_bounds__(256) void build_rowptr(const int* __restrict__ row,
                                                    int* __restrict__ rowptr) {
    const int i = blockIdx.x * 256 + threadIdx.x;
    if (i > N_NODES) return;
    int lo = 0, hi = N_EDGES;
    while (lo < hi) {
        int mid = (lo + hi) >> 1;
        if (row[mid] < i) lo = mid + 1; else hi = mid;
    }
    rowptr[i] = lo;
}

// ---------------------------------------------------------------------------
// Kernel 3: out[i,:] = sum over edges of Xp[col[e],:]. One wave per row,
// lane j owns column j; each gather = one coalesced 256B transaction from
// L2/L3 (Xp is 12.8MB). 16-deep batching: an avg-degree (16) row is ONE
// latency exposure. Every row written exactly once -> no memset/atomics.
// ---------------------------------------------------------------------------
__global__ __launch_bounds__(256) void aggregate(const float* __restrict__ Xp,
                                                 const int* __restrict__ col,
                                                 const int* __restrict__ rowptr,
                                                 float* __restrict__ out) {
    const int wid = (blockIdx.x * 256 + threadIdx.x) >> 6; // row id
    const int j   = threadIdx.x & 63;                      // output col

    const int lo = rowptr[wid];
    const int hi = rowptr[wid + 1];

    float acc = 0.f;
    int e = lo;
    for (; e + 16 <= hi; e += 16) {
        float v[16];
        #pragma unroll
        for (int q = 0; q < 16; ++q) v[q] = Xp[(size_t)col[e + q] * D_OUT + j];
        acc += (((v[0] + v[1]) + (v[2] + v[3])) + ((v[4] + v[5]) + (v[6] + v[7])))
             + (((v[8] + v[9]) + (v[10] + v[11])) + ((v[12] + v[13]) + (v[14] + v[15])));
    }
    for (; e + 4 <= hi; e += 4) {
        float v0 = Xp[(size_t)col[e + 0] * D_OUT + j];
        float v1 = Xp[(size_t)col[e + 1] * D_OUT + j];
        float v2 = Xp[(size_t)col[e + 2] * D_OUT + j];
        float v3 = Xp[(size_t)col[e + 3] * D_OUT + j];
        acc += (v0 + v1) + (v2 + v3);
    }
    for (; e < hi; ++e) {
        acc += Xp[(size_t)col[e] * D_OUT + j];
    }
    out[(size_t)wid * D_OUT + j] = acc;
}

// ---------------------------------------------------------------------------
extern "C" void kernel_launch(void* const* d_in, const int* in_sizes, int n_in,
                              void* d_out, int out_size, void* d_ws, size_t ws_size,
                              hipStream_t stream) {
    const float* X   = (const float*)d_in[0];
    const float* W   = (const float*)d_in[1];
    const int*   row = (const int*)d_in[2];
    const int*   col = (const int*)d_in[3];
    float*       out = (float*)d_out;

    // workspace layout: Xp [50000*64 f32 = 12.8MB] | rowptr [(N+1) i32]
    float* Xp     = (float*)d_ws;
    int*   rowptr = (int*)((char*)d_ws + (size_t)N_NODES * D_OUT * sizeof(float));

    // GEMM: 64-row tiles -> ceil(50000/64) = 782 blocks
    hipLaunchKernelGGL(gemm_xw, dim3((N_NODES + GROWS - 1) / GROWS), dim3(256), 0, stream,
                       X, W, Xp);
    // row_ptr: N_NODES+1 searches
    hipLaunchKernelGGL(build_rowptr, dim3((N_NODES + 1 + 255) / 256), dim3(256), 0, stream,
                       row, rowptr);
    // aggregation: one wave per row -> 50000 waves = 12500 blocks of 4 waves
    hipLaunchKernelGGL(aggregate, dim3((N_NODES * 64) / 256), dim3(256), 0, stream,
                       Xp, col, rowptr, out);
}